// Round 3
// baseline (425.568 us; speedup 1.0000x reference)
//
#include <hip/hip_runtime.h>

// RoI Align 14x14, bilinear, spatial_scale = 0.0625.
// features: (N=2, C=512, H=100, W=152) fp32 NCHW
// rois:     (R=512, 5) fp32
// out:      (R, 512, 14, 14) fp32
//
// Pass 1: NCHW -> NHWC transpose into workspace (62 MB).
// Pass 2: channel-coalesced gather, 4 channels/lane (float4 = 1 KB per
//         wave-load), staged through a conflict-free LDS tile and written
//         back NCHW-coalesced. 8 blocks/CU co-resident (LDS < 20 KB).

#define AH 14
#define AW 14
#define NB (AH * AW)            // 196

constexpr int Nn  = 2;
constexpr int Cc  = 512;
constexpr int Hh  = 100;
constexpr int Ww  = 152;
constexpr int HW  = Hh * Ww;    // 15200
constexpr int CPB = 256;        // channels per block (4 per lane)
constexpr int BHB = 98;         // bins per block (half of 196)
constexpr int PB  = 16;         // bins per staging pass

// ---------------------------------------------------------------- transpose
// Per batch: A[C][HW] -> B[HW][C], 64x64 tiles via LDS.
__global__ __launch_bounds__(256)
void nchw_to_nhwc(const float* __restrict__ feat, float* __restrict__ nhwc)
{
    __shared__ float tile[64][65];

    const int n  = blockIdx.z;
    const int s0 = blockIdx.x * 64;
    const int c0 = blockIdx.y * 64;
    const int tx = threadIdx.x & 63;
    const int ty = threadIdx.x >> 6;        // 0..3

    const float* A = feat + (size_t)n * Cc * HW;
    float*       B = nhwc + (size_t)n * HW * Cc;

    if (s0 + tx < HW) {
        #pragma unroll
        for (int i = 0; i < 16; ++i) {
            const int cl = ty + 4 * i;
            tile[cl][tx] = A[(size_t)(c0 + cl) * HW + (s0 + tx)];
        }
    }
    __syncthreads();
    #pragma unroll
    for (int i = 0; i < 16; ++i) {
        const int sl = ty + 4 * i;
        if (s0 + sl < HW)
            B[(size_t)(s0 + sl) * Cc + (c0 + tx)] = tile[tx][sl];
    }
}

// ---------------------------------------------------------------- main
// grid: (R, 2 channel-groups, 2 bin-halves); 256 threads.
__global__ __launch_bounds__(256, 8)
void roi_align_nhwc4(const float* __restrict__ nhwc,
                     const float* __restrict__ rois,
                     float* __restrict__ out)
{
    const int r    = blockIdx.x;
    const int c0   = blockIdx.y * CPB;
    const int b0   = blockIdx.z * BHB;
    const int tid  = threadIdx.x;
    const int lane = tid & 63;
    const int wid  = tid >> 6;

    __shared__ int4   s_off[BHB];      // tap offsets (floats, pre-scaled by C=512)
    __shared__ float4 s_w[BHB];        // bilinear weights
    __shared__ int    s_base;          // batch base (floats)
    __shared__ float4 T4[PB * 65];     // staging tile: [bin][64 lanes], stride 65

    const float* roi = rois + r * 5;
    const float x_start = roi[1] * 0.0625f;
    const float y_start = roi[2] * 0.0625f;
    const float roi_w = fmaxf(roi[3] * 0.0625f - x_start, 0.0f);
    const float roi_h = fmaxf(roi[4] * 0.0625f - y_start, 0.0f);
    const float bin_h = roi_h / (float)(AH - 1);
    const float bin_w = roi_w / (float)(AW - 1);

    if (tid == 0)
        s_base = ((int)roi[0]) * (HW * Cc);

    if (tid < BHB) {
        const int bin = b0 + tid;
        const int ph = bin / AW;
        const int pw = bin - ph * AW;
        float ys = y_start + (float)ph * bin_h;
        float xs = x_start + (float)pw * bin_w;
        ys = fminf(fmaxf(ys, 0.0f), (float)(Hh - 1));
        xs = fminf(fmaxf(xs, 0.0f), (float)(Ww - 1));
        const int y0 = (int)floorf(ys);
        const int x0 = (int)floorf(xs);
        const int y1 = min(y0 + 1, Hh - 1);
        const int x1 = min(x0 + 1, Ww - 1);
        const float wy = ys - (float)y0;
        const float wx = xs - (float)x0;
        s_off[tid] = make_int4((y0 * Ww + x0) << 9, (y0 * Ww + x1) << 9,
                               (y1 * Ww + x0) << 9, (y1 * Ww + x1) << 9);
        s_w[tid]   = make_float4((1.0f - wy) * (1.0f - wx),
                                 (1.0f - wy) * wx,
                                 wy * (1.0f - wx),
                                 wy * wx);
    }
    __syncthreads();

    const float* fb = nhwc + s_base + c0 + 4 * lane;   // 16B-aligned
    float* __restrict__ outr = out + (size_t)r * (Cc * NB);
    const float* Tf = (const float*)T4;

    for (int p = 0; p < BHB; p += PB) {                // 0,16,...,96
        const int nb = min(PB, BHB - p);               // 16 (x6), then 2

        // gather + bilinear: wave w -> bins p + {w, w+4, w+8, w+12}
        for (int bl = wid; bl < nb; bl += 4) {
            const int4   o = s_off[p + bl];
            const float4 w = s_w[p + bl];
            const float4 t0 = *(const float4*)(fb + o.x);
            const float4 t1 = *(const float4*)(fb + o.y);
            const float4 t2 = *(const float4*)(fb + o.z);
            const float4 t3 = *(const float4*)(fb + o.w);
            float4 v;
            v.x = t0.x * w.x + t1.x * w.y + t2.x * w.z + t3.x * w.w;
            v.y = t0.y * w.x + t1.y * w.y + t2.y * w.z + t3.y * w.w;
            v.z = t0.z * w.x + t1.z * w.y + t2.z * w.z + t3.z * w.w;
            v.w = t0.w * w.x + t1.w * w.y + t2.w * w.z + t3.w * w.w;
            T4[bl * 65 + lane] = v;
        }
        __syncthreads();

        // write out NCHW-coalesced
        if (nb == PB) {
            #pragma unroll
            for (int it = 0; it < PB; ++it) {          // 16*256 = 4096 elems
                const int idx = it * 256 + tid;
                const int cl  = idx >> 4;              // channel-local 0..255
                const int bl  = idx & 15;
                outr[(c0 + cl) * NB + b0 + p + bl] = Tf[bl * 260 + cl];
            }
        } else {                                       // tail: nb == 2
            const int idx = tid;                       // 2*256 = 512 elems
            if (idx < nb * CPB) {
                const int cl = idx >> 1;
                const int bl = idx & 1;
                outr[(c0 + cl) * NB + b0 + p + bl] = Tf[bl * 260 + cl];
            }
            const int idx2 = 256 + tid;
            if (idx2 < nb * CPB) {
                const int cl = idx2 >> 1;
                const int bl = idx2 & 1;
                outr[(c0 + cl) * NB + b0 + p + bl] = Tf[bl * 260 + cl];
            }
        }
        __syncthreads();
    }
}

// ---------------------------------------------------------------- fallback
__global__ __launch_bounds__(256)
void roi_align_nchw(const float* __restrict__ feat,
                    const float* __restrict__ rois,
                    float* __restrict__ out)
{
    const int r  = blockIdx.x;
    const int c0 = blockIdx.y * 128;

    __shared__ int4   s_off[NB];
    __shared__ float4 s_w[NB];
    __shared__ int    s_base;

    const float* roi = rois + r * 5;
    const float x_start = roi[1] * 0.0625f;
    const float y_start = roi[2] * 0.0625f;
    const float roi_w = fmaxf(roi[3] * 0.0625f - x_start, 0.0f);
    const float roi_h = fmaxf(roi[4] * 0.0625f - y_start, 0.0f);
    const float bin_h = roi_h / (float)(AH - 1);
    const float bin_w = roi_w / (float)(AW - 1);

    if (threadIdx.x == 0)
        s_base = ((int)roi[0]) * (Cc * HW);

    for (int i = threadIdx.x; i < NB; i += blockDim.x) {
        const int ph = i / AW;
        const int pw = i - ph * AW;
        float ys = y_start + (float)ph * bin_h;
        float xs = x_start + (float)pw * bin_w;
        ys = fminf(fmaxf(ys, 0.0f), (float)(Hh - 1));
        xs = fminf(fmaxf(xs, 0.0f), (float)(Ww - 1));
        const int y0 = (int)floorf(ys);
        const int x0 = (int)floorf(xs);
        const int y1 = min(y0 + 1, Hh - 1);
        const int x1 = min(x0 + 1, Ww - 1);
        const float wy = ys - (float)y0;
        const float wx = xs - (float)x0;
        s_off[i] = make_int4(y0 * Ww + x0, y0 * Ww + x1,
                             y1 * Ww + x0, y1 * Ww + x1);
        s_w[i]   = make_float4((1.0f - wy) * (1.0f - wx),
                               (1.0f - wy) * wx,
                               wy * (1.0f - wx),
                               wy * wx);
    }
    __syncthreads();

    const int base = s_base;
    float* __restrict__ outr = out + (size_t)r * (Cc * NB);
    const int jend = (c0 + 128) * NB;
    for (int j = c0 * NB + (int)threadIdx.x * 4; j < jend; j += 256 * 4) {
        const int c   = j / NB;
        const int bin = j - c * NB;
        const float* f = feat + base + c * HW;
        float4 v;
        { const int4 o=s_off[bin];   const float4 w=s_w[bin];
          v.x = w.x*f[o.x]+w.y*f[o.y]+w.z*f[o.z]+w.w*f[o.w]; }
        { const int4 o=s_off[bin+1]; const float4 w=s_w[bin+1];
          v.y = w.x*f[o.x]+w.y*f[o.y]+w.z*f[o.z]+w.w*f[o.w]; }
        { const int4 o=s_off[bin+2]; const float4 w=s_w[bin+2];
          v.z = w.x*f[o.x]+w.y*f[o.y]+w.z*f[o.z]+w.w*f[o.w]; }
        { const int4 o=s_off[bin+3]; const float4 w=s_w[bin+3];
          v.w = w.x*f[o.x]+w.y*f[o.y]+w.z*f[o.z]+w.w*f[o.w]; }
        *(float4*)(outr + j) = v;
    }
}

extern "C" void kernel_launch(void* const* d_in, const int* in_sizes, int n_in,
                              void* d_out, int out_size, void* d_ws, size_t ws_size,
                              hipStream_t stream)
{
    const float* feat = (const float*)d_in[0];
    const float* rois = (const float*)d_in[1];
    float*       out  = (float*)d_out;
    const int R = in_sizes[1] / 5;                       // 512

    const size_t need = (size_t)Nn * HW * Cc * sizeof(float);   // 62.26 MB
    if (ws_size >= need) {
        float* nhwc = (float*)d_ws;
        dim3 tg((HW + 63) / 64, Cc / 64, Nn);            // (238, 8, 2)
        nchw_to_nhwc<<<tg, 256, 0, stream>>>(feat, nhwc);
        dim3 mg(R, Cc / CPB, NB / BHB);                  // (512, 2, 2)
        roi_align_nhwc4<<<mg, 256, 0, stream>>>(nhwc, rois, out);
    } else {
        dim3 grid(R, Cc / 128);
        roi_align_nchw<<<grid, 256, 0, stream>>>(feat, rois, out);
    }
}